// Round 1
// baseline (815.614 us; speedup 1.0000x reference)
//
#include <hip/hip_runtime.h>

#define N_IMG 100000
#define C_CLS 1000
#define DIM   512     // att_dim == img_dim == 512
#define HPROJ 256     // H

// ---------------------------------------------------------------------------
// K1: per-class mean pooling (segment mean), zero global atomics.
// Block c scans labels into an LDS list, then gathers matching rows coalesced.
// ---------------------------------------------------------------------------
__global__ __launch_bounds__(256) void protos_kernel(
    const float* __restrict__ image_feats,   // [N, 512]
    const int*   __restrict__ labels,        // [N]
    float*       __restrict__ protos,        // [C, 512]
    int n)
{
    __shared__ int s_list[2048];
    __shared__ int s_cnt;
    const int c = blockIdx.x;
    const int t = threadIdx.x;
    if (t == 0) s_cnt = 0;
    __syncthreads();
    for (int i = t; i < n; i += 256) {
        if (labels[i] == c) {
            int p = atomicAdd(&s_cnt, 1);
            if (p < 2048) s_list[p] = i;
        }
    }
    __syncthreads();
    const int cnt = s_cnt;
    const int col = t * 2;
    float2 acc = {0.f, 0.f};
    for (int m = 0; m < cnt; ++m) {
        const int row = s_list[m];
        const float2 v = *(const float2*)(image_feats + (size_t)row * DIM + col);
        acc.x += v.x; acc.y += v.y;
    }
    const float inv = 1.0f / (float)cnt;
    float2 o = {acc.x * inv, acc.y * inv};
    *(float2*)(protos + (size_t)c * DIM + col) = o;
}

// ---------------------------------------------------------------------------
// K2/K4: Xn = normalize_rows(A @ Wm); also store transpose XnT for coalesced
// j-access in the attention kernel.  A:[C,512], Wm:[512,256].
// ---------------------------------------------------------------------------
__global__ __launch_bounds__(256) void projnorm_kernel(
    const float* __restrict__ A,    // [C, 512]
    const float* __restrict__ Wm,   // [512, 256]
    float*       __restrict__ Xn,   // [C, 256]
    float*       __restrict__ XnT)  // [256, C]
{
    __shared__ float s_a[DIM];
    __shared__ float s_red[5];
    const int i = blockIdx.x;
    const int t = threadIdx.x;
    *(float2*)(s_a + 2 * t) = *(const float2*)(A + (size_t)i * DIM + 2 * t);
    __syncthreads();
    float v = 0.f;
#pragma unroll 8
    for (int k = 0; k < DIM; ++k)
        v = fmaf(s_a[k], Wm[k * HPROJ + t], v);
    // sum of squares over 256 threads (4 waves)
    float ss = v * v;
#pragma unroll
    for (int off = 32; off > 0; off >>= 1) ss += __shfl_down(ss, off);
    if ((t & 63) == 0) s_red[t >> 6] = ss;
    __syncthreads();
    if (t == 0) s_red[4] = rsqrtf(s_red[0] + s_red[1] + s_red[2] + s_red[3]);
    __syncthreads();
    const float rn = s_red[4];
    const float xv = v * rn;
    Xn[(size_t)i * HPROJ + t] = xv;
    XnT[(size_t)t * C_CLS + i] = xv;
}

// ---------------------------------------------------------------------------
// K3/K5: Out[i,:] = softmax_j( mask(cos_ij) * 10 ) @ V   for ROWS rows per
// block.  cos via pre-normalized Xn/XnT; masked terms are exactly 0.
// vidx==nullptr -> V rows indexed by j directly; else gather V[vidx[j]].
// ---------------------------------------------------------------------------
#define ROWS 4
__global__ __launch_bounds__(256) void attn_mm_kernel(
    const float* __restrict__ Xn,    // [C, 256]
    const float* __restrict__ XnT,   // [256, C]
    const float* __restrict__ V,     // [C, 512]
    const int*   __restrict__ vidx,  // nullptr or [C]
    float*       __restrict__ Out)   // [C, 512]
{
    __shared__ float s_x[ROWS][HPROJ];
    __shared__ float s_w[ROWS][C_CLS];
    __shared__ float s_red[ROWS][4];
    __shared__ float s_rs[ROWS];
    const int t  = threadIdx.x;
    const int r0 = blockIdx.x * ROWS;

    for (int idx = t; idx < ROWS * HPROJ; idx += 256) {
        const int i = idx >> 8, k = idx & 255;
        s_x[i][k] = Xn[(size_t)(r0 + i) * HPROJ + k];
    }
    __syncthreads();

    // --- scores: d[i][u] = dot(s_x[i], Xn[j])  with j = t + 256*u ---
    float d0[ROWS][4];
#pragma unroll
    for (int i = 0; i < ROWS; ++i)
#pragma unroll
        for (int u = 0; u < 4; ++u) d0[i][u] = 0.f;
    int jj[4];
#pragma unroll
    for (int u = 0; u < 4; ++u) {
        const int j = t + 256 * u;
        jj[u] = (j < C_CLS) ? j : (C_CLS - 1);   // clamp for loads
    }
#pragma unroll 2
    for (int k = 0; k < HPROJ; ++k) {
        const float* xt = XnT + (size_t)k * C_CLS;
        float pj[4];
#pragma unroll
        for (int u = 0; u < 4; ++u) pj[u] = xt[jj[u]];
#pragma unroll
        for (int i = 0; i < ROWS; ++i) {
            const float xk = s_x[i][k];
#pragma unroll
            for (int u = 0; u < 4; ++u) d0[i][u] = fmaf(xk, pj[u], d0[i][u]);
        }
    }

    // --- mask + exp(10*d), stash weights, partial row sums ---
    float ps[ROWS];
#pragma unroll
    for (int i = 0; i < ROWS; ++i) ps[i] = 0.f;
#pragma unroll
    for (int u = 0; u < 4; ++u) {
        const int j = t + 256 * u;
        if (j < C_CLS) {
#pragma unroll
            for (int i = 0; i < ROWS; ++i) {
                const float dv = d0[i][u];
                const float w  = (dv > 0.5f) ? __expf(dv * 10.f) : 0.f;
                s_w[i][j] = w;
                ps[i] += w;
            }
        }
    }
    // row-sum reduction over 256 threads
#pragma unroll
    for (int off = 32; off > 0; off >>= 1)
#pragma unroll
        for (int i = 0; i < ROWS; ++i) ps[i] += __shfl_down(ps[i], off);
    if ((t & 63) == 0) {
        const int wv = t >> 6;
#pragma unroll
        for (int i = 0; i < ROWS; ++i) s_red[i][wv] = ps[i];
    }
    __syncthreads();
    if (t < ROWS)
        s_rs[t] = 1.f / (s_red[t][0] + s_red[t][1] + s_red[t][2] + s_red[t][3]);
    __syncthreads();

    // --- weighted sum over V rows: each thread owns 2 output columns ---
    const int col = 2 * t;
    float2 acc[ROWS];
#pragma unroll
    for (int i = 0; i < ROWS; ++i) { acc[i].x = 0.f; acc[i].y = 0.f; }
    for (int j = 0; j < C_CLS; ++j) {
        const int row = vidx ? vidx[j] : j;
        const float2 v2 = *(const float2*)(V + (size_t)row * DIM + col);
#pragma unroll
        for (int i = 0; i < ROWS; ++i) {
            const float w = s_w[i][j];
            acc[i].x = fmaf(w, v2.x, acc[i].x);
            acc[i].y = fmaf(w, v2.y, acc[i].y);
        }
    }
#pragma unroll
    for (int i = 0; i < ROWS; ++i) {
        const float s = s_rs[i];
        float2 o = {acc[i].x * s, acc[i].y * s};
        *(float2*)(Out + (size_t)(r0 + i) * DIM + col) = o;
    }
}

// ---------------------------------------------------------------------------
extern "C" void kernel_launch(void* const* d_in, const int* in_sizes, int n_in,
                              void* d_out, int out_size, void* d_ws, size_t ws_size,
                              hipStream_t stream) {
    const float* image_feats = (const float*)d_in[0];  // [100000, 512]
    const float* attributes  = (const float*)d_in[1];  // [1000, 512]
    const float* att_g       = (const float*)d_in[2];  // [512, 256]
    const float* att_h       = (const float*)d_in[3];  // [512, 256]
    const int*   labels      = (const int*)d_in[4];    // [100000]
    const int*   tpl         = (const int*)d_in[5];    // [1000]
    float* out = (float*)d_out;                        // [1000, 512]

    float* ws     = (float*)d_ws;
    float* protos = ws;                  // 512000
    float* p_n    = protos + 512000;     // 256000
    float* p_nT   = p_n + 256000;        // 256000
    float* enc    = p_nT + 256000;       // 512000
    // q_n / q_nT alias p_n / p_nT (p dead after enc is computed)
    float* q_n  = p_n;
    float* q_nT = p_nT;

    protos_kernel<<<C_CLS, 256, 0, stream>>>(image_feats, labels, protos, N_IMG);
    projnorm_kernel<<<C_CLS, 256, 0, stream>>>(attributes, att_h, p_n, p_nT);
    attn_mm_kernel<<<C_CLS / ROWS, 256, 0, stream>>>(p_n, p_nT, attributes, nullptr, enc);
    projnorm_kernel<<<C_CLS, 256, 0, stream>>>(enc, att_g, q_n, q_nT);
    attn_mm_kernel<<<C_CLS / ROWS, 256, 0, stream>>>(q_n, q_nT, protos, tpl, out);
}

// Round 2
// 657.848 us; speedup vs baseline: 1.2398x; 1.2398x over previous
//
#include <hip/hip_runtime.h>

#define N_IMG 100000
#define C_CLS 1000
#define DIM   512     // att_dim == img_dim == 512
#define HPROJ 256     // H
#define CAP   512     // per-class bucket capacity (mean count=100, max ~150)

// ---------------------------------------------------------------------------
// K0: one pass over labels -> per-class row lists. cnt[] must be zeroed.
// ---------------------------------------------------------------------------
__global__ __launch_bounds__(256) void fill_kernel(
    const int* __restrict__ labels, int* __restrict__ cnt,
    int* __restrict__ perm, int n)
{
    const int i = blockIdx.x * 256 + threadIdx.x;
    if (i < n) {
        const int c = labels[i];
        const int p = atomicAdd(&cnt[c], 1);
        if (p < CAP) perm[c * CAP + p] = i;
    }
}

// ---------------------------------------------------------------------------
// K1: per-class mean. Block c gathers its rows; float4 loads, 2 rows/iter.
// ---------------------------------------------------------------------------
__global__ __launch_bounds__(256) void gather_kernel(
    const float* __restrict__ image_feats,   // [N, 512]
    const int*   __restrict__ cnt,
    const int*   __restrict__ perm,
    float*       __restrict__ protos)        // [C, 512]
{
    __shared__ int    s_list[CAP];
    __shared__ float4 s_acc[128];
    const int c = blockIdx.x;
    const int t = threadIdx.x;
    const int n = min(cnt[c], CAP);
    for (int m = t; m < n; m += 256) s_list[m] = perm[c * CAP + m];
    __syncthreads();
    const int half = t >> 7;          // 0: even-listed rows, 1: odd-listed
    const int tc   = t & 127;         // column group (4 floats)
    float4 acc = {0.f, 0.f, 0.f, 0.f};
    for (int m = half; m < n; m += 2) {
        const float4 v = *(const float4*)(image_feats + (size_t)s_list[m] * DIM + 4 * tc);
        acc.x += v.x; acc.y += v.y; acc.z += v.z; acc.w += v.w;
    }
    if (half) s_acc[tc] = acc;
    __syncthreads();
    if (!half) {
        const float4 o = s_acc[tc];
        const float inv = 1.0f / (float)n;
        float4 r;
        r.x = (acc.x + o.x) * inv; r.y = (acc.y + o.y) * inv;
        r.z = (acc.z + o.z) * inv; r.w = (acc.w + o.w) * inv;
        *(float4*)(protos + (size_t)c * DIM + 4 * tc) = r;
    }
}

// ---------------------------------------------------------------------------
// K2/K4: Xn = normalize_rows(A @ Wm), 4 rows per block (each Wm load feeds
// 4 FMAs). Also stores transpose XnT (float4 store per thread).
// ---------------------------------------------------------------------------
#define PROWS 4
__global__ __launch_bounds__(256) void projnorm_kernel(
    const float* __restrict__ A,    // [C, 512]
    const float* __restrict__ Wm,   // [512, 256]
    float*       __restrict__ Xn,   // [C, 256]
    float*       __restrict__ XnT)  // [256, C]
{
    __shared__ float s_a[PROWS][DIM];
    __shared__ float s_red[PROWS][4];
    __shared__ float s_rn[PROWS];
    const int t  = threadIdx.x;
    const int i0 = blockIdx.x * PROWS;
    for (int idx = t; idx < PROWS * DIM; idx += 256) {
        const int i = idx >> 9, k = idx & 511;
        s_a[i][k] = A[(size_t)(i0 + i) * DIM + k];
    }
    __syncthreads();
    float acc[PROWS] = {0.f, 0.f, 0.f, 0.f};
#pragma unroll 8
    for (int k = 0; k < DIM; ++k) {
        const float w = Wm[k * HPROJ + t];
#pragma unroll
        for (int i = 0; i < PROWS; ++i) acc[i] = fmaf(s_a[i][k], w, acc[i]);
    }
    float ss[PROWS];
#pragma unroll
    for (int i = 0; i < PROWS; ++i) ss[i] = acc[i] * acc[i];
#pragma unroll
    for (int off = 32; off > 0; off >>= 1)
#pragma unroll
        for (int i = 0; i < PROWS; ++i) ss[i] += __shfl_down(ss[i], off);
    if ((t & 63) == 0) {
        const int wv = t >> 6;
#pragma unroll
        for (int i = 0; i < PROWS; ++i) s_red[i][wv] = ss[i];
    }
    __syncthreads();
    if (t < PROWS)
        s_rn[t] = rsqrtf(s_red[t][0] + s_red[t][1] + s_red[t][2] + s_red[t][3]);
    __syncthreads();
    float4 tv;
#pragma unroll
    for (int i = 0; i < PROWS; ++i) {
        const float xv = acc[i] * s_rn[i];
        Xn[(size_t)(i0 + i) * HPROJ + t] = xv;
        ((float*)&tv)[i] = xv;
    }
    *(float4*)(XnT + (size_t)t * C_CLS + i0) = tv;   // t*1000*4 and i0*4 are 16B-aligned
}

// ---------------------------------------------------------------------------
// K3/K5: Out[i,:] = softmax_j( mask(cos_ij)*10 ) @ V for ROWS rows per block.
// ---------------------------------------------------------------------------
#define ROWS 4
__global__ __launch_bounds__(256) void attn_mm_kernel(
    const float* __restrict__ Xn,    // [C, 256]
    const float* __restrict__ XnT,   // [256, C]
    const float* __restrict__ V,     // [C, 512]
    const int*   __restrict__ vidx,  // nullptr or [C]
    float*       __restrict__ Out)   // [C, 512]
{
    __shared__ float s_x[ROWS][HPROJ];
    __shared__ float s_w[ROWS][C_CLS];
    __shared__ int   s_vi[C_CLS];
    __shared__ float s_red[ROWS][4];
    __shared__ float s_rs[ROWS];
    const int t  = threadIdx.x;
    const int r0 = blockIdx.x * ROWS;

    for (int idx = t; idx < ROWS * HPROJ; idx += 256) {
        const int i = idx >> 8, k = idx & 255;
        s_x[i][k] = Xn[(size_t)(r0 + i) * HPROJ + k];
    }
    if (vidx) for (int j = t; j < C_CLS; j += 256) s_vi[j] = vidx[j];
    __syncthreads();

    // --- scores: d[i][u] = dot(s_x[i], col j of XnT), j = t + 256*u ---
    float d0[ROWS][4];
#pragma unroll
    for (int i = 0; i < ROWS; ++i)
#pragma unroll
        for (int u = 0; u < 4; ++u) d0[i][u] = 0.f;
    int jj[4];
#pragma unroll
    for (int u = 0; u < 4; ++u) {
        const int j = t + 256 * u;
        jj[u] = (j < C_CLS) ? j : (C_CLS - 1);
    }
#pragma unroll 4
    for (int k = 0; k < HPROJ; ++k) {
        const float* xt = XnT + (size_t)k * C_CLS;
        float pj[4];
#pragma unroll
        for (int u = 0; u < 4; ++u) pj[u] = xt[jj[u]];
#pragma unroll
        for (int i = 0; i < ROWS; ++i) {
            const float xk = s_x[i][k];
#pragma unroll
            for (int u = 0; u < 4; ++u) d0[i][u] = fmaf(xk, pj[u], d0[i][u]);
        }
    }

    // --- mask + exp(10*d), stash weights, partial row sums ---
    float ps[ROWS];
#pragma unroll
    for (int i = 0; i < ROWS; ++i) ps[i] = 0.f;
#pragma unroll
    for (int u = 0; u < 4; ++u) {
        const int j = t + 256 * u;
        if (j < C_CLS) {
#pragma unroll
            for (int i = 0; i < ROWS; ++i) {
                const float dv = d0[i][u];
                const float w  = (dv > 0.5f) ? __expf(dv * 10.f) : 0.f;
                s_w[i][j] = w;
                ps[i] += w;
            }
        }
    }
#pragma unroll
    for (int off = 32; off > 0; off >>= 1)
#pragma unroll
        for (int i = 0; i < ROWS; ++i) ps[i] += __shfl_down(ps[i], off);
    if ((t & 63) == 0) {
        const int wv = t >> 6;
#pragma unroll
        for (int i = 0; i < ROWS; ++i) s_red[i][wv] = ps[i];
    }
    __syncthreads();
    if (t < ROWS)
        s_rs[t] = 1.f / (s_red[t][0] + s_red[t][1] + s_red[t][2] + s_red[t][3]);
    __syncthreads();

    // --- weighted sum over V rows, j unrolled x4 with batched loads ---
    const int col = 2 * t;
    float2 acc[ROWS];
#pragma unroll
    for (int i = 0; i < ROWS; ++i) { acc[i].x = 0.f; acc[i].y = 0.f; }
    for (int j = 0; j < C_CLS; j += 4) {
        float2 v2[4];
#pragma unroll
        for (int u = 0; u < 4; ++u) {
            const int row = vidx ? s_vi[j + u] : (j + u);
            v2[u] = *(const float2*)(V + (size_t)row * DIM + col);
        }
#pragma unroll
        for (int u = 0; u < 4; ++u)
#pragma unroll
            for (int i = 0; i < ROWS; ++i) {
                const float w = s_w[i][j + u];
                acc[i].x = fmaf(w, v2[u].x, acc[i].x);
                acc[i].y = fmaf(w, v2[u].y, acc[i].y);
            }
    }
#pragma unroll
    for (int i = 0; i < ROWS; ++i) {
        const float s = s_rs[i];
        float2 o = {acc[i].x * s, acc[i].y * s};
        *(float2*)(Out + (size_t)(r0 + i) * DIM + col) = o;
    }
}

// ---------------------------------------------------------------------------
extern "C" void kernel_launch(void* const* d_in, const int* in_sizes, int n_in,
                              void* d_out, int out_size, void* d_ws, size_t ws_size,
                              hipStream_t stream) {
    const float* image_feats = (const float*)d_in[0];  // [100000, 512]
    const float* attributes  = (const float*)d_in[1];  // [1000, 512]
    const float* att_g       = (const float*)d_in[2];  // [512, 256]
    const float* att_h       = (const float*)d_in[3];  // [512, 256]
    const int*   labels      = (const int*)d_in[4];    // [100000]
    const int*   tpl         = (const int*)d_in[5];    // [1000]
    float* out = (float*)d_out;                        // [1000, 512]

    float* ws     = (float*)d_ws;
    float* protos = ws;                  // 512000 f
    float* p_n    = protos + 512000;     // 256000 f
    float* p_nT   = p_n + 256000;        // 256000 f
    float* enc    = p_nT + 256000;       // 512000 f
    int*   cnt    = (int*)(enc + 512000);    // 1000 i
    int*   perm   = cnt + 1024;              // 1000*512 i
    // q_n / q_nT alias p_n / p_nT (p dead after enc is computed)
    float* q_n  = p_n;
    float* q_nT = p_nT;

    hipMemsetAsync(cnt, 0, C_CLS * sizeof(int), stream);
    fill_kernel<<<(N_IMG + 255) / 256, 256, 0, stream>>>(labels, cnt, perm, N_IMG);
    gather_kernel<<<C_CLS, 256, 0, stream>>>(image_feats, cnt, perm, protos);
    projnorm_kernel<<<C_CLS / PROWS, 256, 0, stream>>>(attributes, att_h, p_n, p_nT);
    attn_mm_kernel<<<C_CLS / ROWS, 256, 0, stream>>>(p_n, p_nT, attributes, nullptr, enc);
    projnorm_kernel<<<C_CLS / PROWS, 256, 0, stream>>>(enc, att_g, q_n, q_nT);
    attn_mm_kernel<<<C_CLS / ROWS, 256, 0, stream>>>(q_n, q_nT, protos, tpl, out);
}

// Round 3
// 474.729 us; speedup vs baseline: 1.7181x; 1.3857x over previous
//
#include <hip/hip_runtime.h>

#define N_IMG 100000
#define C_CLS 1000
#define CP    1024    // padded class count
#define DIM   512     // att_dim == img_dim
#define HPROJ 256     // H
#define CAP   512     // per-class bucket capacity

// ---------------------------------------------------------------------------
// K0: one pass over labels -> per-class row lists. cnt[] must be zeroed.
// ---------------------------------------------------------------------------
__global__ __launch_bounds__(256) void fill_kernel(
    const int* __restrict__ labels, int* __restrict__ cnt,
    int* __restrict__ perm, int n)
{
    const int i = blockIdx.x * 256 + threadIdx.x;
    if (i < n) {
        const int c = labels[i];
        const int p = atomicAdd(&cnt[c], 1);
        if (p < CAP) perm[c * CAP + p] = i;
    }
}

// ---------------------------------------------------------------------------
// K1: per-class mean; float4 loads, 2 row-streams x unroll-2.
// ---------------------------------------------------------------------------
__global__ __launch_bounds__(256) void gather_kernel(
    const float* __restrict__ image_feats,   // [N, 512]
    const int*   __restrict__ cnt,
    const int*   __restrict__ perm,
    float*       __restrict__ protos)        // [1000, 512]
{
    __shared__ int    s_list[CAP];
    __shared__ float4 s_acc[128];
    const int c = blockIdx.x;
    const int t = threadIdx.x;
    const int n = min(cnt[c], CAP);
    for (int m = t; m < n; m += 256) s_list[m] = perm[c * CAP + m];
    __syncthreads();
    const int half = t >> 7;
    const int tc   = t & 127;
    float4 a0 = {0.f,0.f,0.f,0.f}, a1 = {0.f,0.f,0.f,0.f};
    int m = half;
    for (; m + 2 < n; m += 4) {
        const float4 v0 = *(const float4*)(image_feats + (size_t)s_list[m]     * DIM + 4 * tc);
        const float4 v1 = *(const float4*)(image_feats + (size_t)s_list[m + 2] * DIM + 4 * tc);
        a0.x += v0.x; a0.y += v0.y; a0.z += v0.z; a0.w += v0.w;
        a1.x += v1.x; a1.y += v1.y; a1.z += v1.z; a1.w += v1.w;
    }
    for (; m < n; m += 2) {
        const float4 v0 = *(const float4*)(image_feats + (size_t)s_list[m] * DIM + 4 * tc);
        a0.x += v0.x; a0.y += v0.y; a0.z += v0.z; a0.w += v0.w;
    }
    a0.x += a1.x; a0.y += a1.y; a0.z += a1.z; a0.w += a1.w;
    if (half) s_acc[tc] = a0;
    __syncthreads();
    if (!half) {
        const float4 o = s_acc[tc];
        const float inv = 1.0f / (float)n;
        float4 r;
        r.x = (a0.x + o.x) * inv; r.y = (a0.y + o.y) * inv;
        r.z = (a0.z + o.z) * inv; r.w = (a0.w + o.w) * inv;
        *(float4*)(protos + (size_t)c * DIM + 4 * tc) = r;
    }
}

// ---------------------------------------------------------------------------
// K2: P[kz] = A @ Wm partial GEMM. Tile 32x32, per-thread 2x2, split-K x2.
// grid(8, 32, 2). A rows clamped to 999.
// ---------------------------------------------------------------------------
__global__ __launch_bounds__(256) void proj_kernel(
    const float* __restrict__ A,    // [1000, 512]
    const float* __restrict__ Wm,   // [512, 256]
    float*       __restrict__ P)    // [2][1024][256]
{
    __shared__ float At[64][34];    // k-major (transposed)
    __shared__ float Wt[64][36];    // k-major (natural)
    const int t  = threadIdx.x;
    const int j0 = blockIdx.x * 32;
    const int i0 = blockIdx.y * 32;
    const int kz = blockIdx.z;
    const int tx = t & 15, ty = t >> 4;
    float a00 = 0.f, a01 = 0.f, a10 = 0.f, a11 = 0.f;
    for (int ch = 0; ch < 4; ++ch) {
        const int kb = kz * 256 + ch * 64;
        __syncthreads();
        for (int l = t; l < 512; l += 256) {
            const int r = l >> 4, f = l & 15;
            const int row = min(i0 + r, C_CLS - 1);
            const float4 v = *(const float4*)(A + (size_t)row * DIM + kb + 4 * f);
            At[4*f+0][r] = v.x; At[4*f+1][r] = v.y; At[4*f+2][r] = v.z; At[4*f+3][r] = v.w;
        }
        for (int l = t; l < 512; l += 256) {
            const int kk = l >> 3, f = l & 7;
            *(float4*)&Wt[kk][4*f] =
                *(const float4*)(Wm + (size_t)(kb + kk) * HPROJ + j0 + 4 * f);
        }
        __syncthreads();
#pragma unroll 8
        for (int kk = 0; kk < 64; ++kk) {
            const float2 a = *(const float2*)&At[kk][2 * ty];
            const float2 b = *(const float2*)&Wt[kk][2 * tx];
            a00 = fmaf(a.x, b.x, a00); a01 = fmaf(a.x, b.y, a01);
            a10 = fmaf(a.y, b.x, a10); a11 = fmaf(a.y, b.y, a11);
        }
    }
    float* dst = P + (size_t)kz * CP * HPROJ;
    {
        const int i = i0 + 2 * ty;
        *(float2*)(dst + (size_t)i * HPROJ + j0 + 2 * tx) = make_float2(a00, a01);
        *(float2*)(dst + (size_t)(i + 1) * HPROJ + j0 + 2 * tx) = make_float2(a10, a11);
    }
}

// ---------------------------------------------------------------------------
// K3: Xn[i] = (P0[i]+P1[i]) row-normalized. grid(1000), 256 thr.
// ---------------------------------------------------------------------------
__global__ __launch_bounds__(256) void norm_kernel(
    const float* __restrict__ P, float* __restrict__ Xn)
{
    __shared__ float red[4];
    __shared__ float rn;
    const int i = blockIdx.x;
    const int t = threadIdx.x;
    const float x = P[(size_t)i * HPROJ + t] + P[(size_t)CP * HPROJ + (size_t)i * HPROJ + t];
    float ss = x * x;
#pragma unroll
    for (int off = 32; off > 0; off >>= 1) ss += __shfl_down(ss, off);
    if ((t & 63) == 0) red[t >> 6] = ss;
    __syncthreads();
    if (t == 0) rn = rsqrtf(red[0] + red[1] + red[2] + red[3]);
    __syncthreads();
    Xn[(size_t)i * HPROJ + t] = x * rn;
}

// ---------------------------------------------------------------------------
// K4: W = maskexp(Xn Xn^T), padded to [1024] cols (0 for j>=1000).
// Tile 32x32, per-thread 2x2, K=256 in 4 chunks. grid(32, 32).
// ---------------------------------------------------------------------------
__global__ __launch_bounds__(256) void score_kernel(
    const float* __restrict__ Xn,   // [1000, 256]
    float*       __restrict__ W)    // [1024][1024], rows >=1000 unwritten
{
    __shared__ float Xi[64][34];
    __shared__ float Xj[64][34];
    const int t  = threadIdx.x;
    const int j0 = blockIdx.x * 32;
    const int i0 = blockIdx.y * 32;
    const int tx = t & 15, ty = t >> 4;
    float a00 = 0.f, a01 = 0.f, a10 = 0.f, a11 = 0.f;
    for (int ch = 0; ch < 4; ++ch) {
        const int kb = ch * 64;
        __syncthreads();
        for (int l = t; l < 512; l += 256) {
            const int r = l >> 4, f = l & 15;
            int row = min(i0 + r, C_CLS - 1);
            float4 v = *(const float4*)(Xn + (size_t)row * HPROJ + kb + 4 * f);
            Xi[4*f+0][r] = v.x; Xi[4*f+1][r] = v.y; Xi[4*f+2][r] = v.z; Xi[4*f+3][r] = v.w;
            row = min(j0 + r, C_CLS - 1);
            v = *(const float4*)(Xn + (size_t)row * HPROJ + kb + 4 * f);
            Xj[4*f+0][r] = v.x; Xj[4*f+1][r] = v.y; Xj[4*f+2][r] = v.z; Xj[4*f+3][r] = v.w;
        }
        __syncthreads();
#pragma unroll 8
        for (int kk = 0; kk < 64; ++kk) {
            const float2 xi = *(const float2*)&Xi[kk][2 * ty];
            const float2 xj = *(const float2*)&Xj[kk][2 * tx];
            a00 = fmaf(xi.x, xj.x, a00); a01 = fmaf(xi.x, xj.y, a01);
            a10 = fmaf(xi.y, xj.x, a10); a11 = fmaf(xi.y, xj.y, a11);
        }
    }
    const int j = j0 + 2 * tx;
    const bool jv0 = (j < C_CLS), jv1 = (j + 1 < C_CLS);
#pragma unroll
    for (int u = 0; u < 2; ++u) {
        const int i = i0 + 2 * ty + u;
        if (i < C_CLS) {
            const float d0 = u ? a10 : a00;
            const float d1 = u ? a11 : a01;
            float2 w;
            w.x = (jv0 && d0 > 0.5f) ? __expf(10.f * d0) : 0.f;
            w.y = (jv1 && d1 > 0.5f) ? __expf(10.f * d1) : 0.f;
            *(float2*)(W + (size_t)i * CP + j) = w;
        }
    }
}

// ---------------------------------------------------------------------------
// K5: rsinv[i] = 1 / sum_j W[i,j]. grid(1000), 256 thr, f4 each.
// ---------------------------------------------------------------------------
__global__ __launch_bounds__(256) void rowsum_kernel(
    const float* __restrict__ W, float* __restrict__ rsinv)
{
    __shared__ float red[4];
    const int i = blockIdx.x;
    const int t = threadIdx.x;
    const float4 v = *(const float4*)(W + (size_t)i * CP + 4 * t);
    float s = v.x + v.y + v.z + v.w;
#pragma unroll
    for (int off = 32; off > 0; off >>= 1) s += __shfl_down(s, off);
    if ((t & 63) == 0) red[t >> 6] = s;
    __syncthreads();
    if (t == 0) rsinv[i] = 1.0f / (red[0] + red[1] + red[2] + red[3]);
}

// ---------------------------------------------------------------------------
// K6: Q[kz] = W @ Vg partial GEMM. Tile 32 rows x 64 cols, per-thread 2x4,
// split-K x2 over K=1024 (pad W cols are 0). grid(8, 32, 2).
// Vg[j] = V[vidx[j]] (or V[j] if vidx==null), j clamped to 999.
// ---------------------------------------------------------------------------
__global__ __launch_bounds__(256) void mm_kernel(
    const float* __restrict__ W,    // [1024][1024] (rows >=1000 garbage, unused)
    const float* __restrict__ V,    // [1000, 512]
    const int*   __restrict__ vidx, // nullptr or [1000]
    float*       __restrict__ Q)    // [2][1024][512]
{
    __shared__ float Wt[64][34];    // k-major (transposed)
    __shared__ float Vt[64][68];    // k-major (natural)
    const int t  = threadIdx.x;
    const int c0 = blockIdx.x * 64;
    const int i0 = blockIdx.y * 32;
    const int kz = blockIdx.z;
    const int tx = t & 15, ty = t >> 4;
    float acc[2][4] = {};
    for (int ch = 0; ch < 8; ++ch) {
        const int kb = kz * 512 + ch * 64;
        __syncthreads();
        for (int l = t; l < 512; l += 256) {
            const int r = l >> 4, f = l & 15;
            const float4 v = *(const float4*)(W + (size_t)(i0 + r) * CP + kb + 4 * f);
            Wt[4*f+0][r] = v.x; Wt[4*f+1][r] = v.y; Wt[4*f+2][r] = v.z; Wt[4*f+3][r] = v.w;
        }
        for (int l = t; l < 1024; l += 256) {
            const int kk = l >> 4, f = l & 15;
            const int jc = min(kb + kk, C_CLS - 1);
            const int vr = vidx ? vidx[jc] : jc;
            *(float4*)&Vt[kk][4*f] = *(const float4*)(V + (size_t)vr * DIM + c0 + 4 * f);
        }
        __syncthreads();
#pragma unroll 4
        for (int kk = 0; kk < 64; ++kk) {
            const float2 w = *(const float2*)&Wt[kk][2 * ty];
            const float4 v = *(const float4*)&Vt[kk][4 * tx];
            acc[0][0] = fmaf(w.x, v.x, acc[0][0]);
            acc[0][1] = fmaf(w.x, v.y, acc[0][1]);
            acc[0][2] = fmaf(w.x, v.z, acc[0][2]);
            acc[0][3] = fmaf(w.x, v.w, acc[0][3]);
            acc[1][0] = fmaf(w.y, v.x, acc[1][0]);
            acc[1][1] = fmaf(w.y, v.y, acc[1][1]);
            acc[1][2] = fmaf(w.y, v.z, acc[1][2]);
            acc[1][3] = fmaf(w.y, v.w, acc[1][3]);
        }
    }
    float* dst = Q + (size_t)kz * CP * DIM;
#pragma unroll
    for (int u = 0; u < 2; ++u) {
        const int i = i0 + 2 * ty + u;
        float4 o = {acc[u][0], acc[u][1], acc[u][2], acc[u][3]};
        *(float4*)(dst + (size_t)i * DIM + c0 + 4 * tx) = o;
    }
}

// ---------------------------------------------------------------------------
// K7: Out[i,c] = rsinv[i] * (Q0[i,c] + Q1[i,c]), i < 1000. grid(500).
// ---------------------------------------------------------------------------
__global__ __launch_bounds__(256) void combine_kernel(
    const float* __restrict__ Q, const float* __restrict__ rsinv,
    float* __restrict__ Out)    // [1000, 512]
{
    const int idx = blockIdx.x * 256 + threadIdx.x;   // f4 index
    if (idx < C_CLS * DIM / 4) {
        const int i = idx >> 7;                        // / (512/4)
        const float4 a = *(const float4*)(Q + (size_t)4 * idx);
        const float4 b = *(const float4*)(Q + (size_t)CP * DIM + (size_t)4 * idx);
        const float s = rsinv[i];
        float4 o;
        o.x = s * (a.x + b.x); o.y = s * (a.y + b.y);
        o.z = s * (a.z + b.z); o.w = s * (a.w + b.w);
        *(float4*)(Out + (size_t)4 * idx) = o;
    }
}

// ---------------------------------------------------------------------------
extern "C" void kernel_launch(void* const* d_in, const int* in_sizes, int n_in,
                              void* d_out, int out_size, void* d_ws, size_t ws_size,
                              hipStream_t stream) {
    const float* image_feats = (const float*)d_in[0];  // [100000, 512]
    const float* attributes  = (const float*)d_in[1];  // [1000, 512]
    const float* att_g       = (const float*)d_in[2];  // [512, 256]
    const float* att_h       = (const float*)d_in[3];  // [512, 256]
    const int*   labels      = (const int*)d_in[4];    // [100000]
    const int*   tpl         = (const int*)d_in[5];    // [1000]
    float* out = (float*)d_out;                        // [1000, 512]

    float* ws     = (float*)d_ws;
    float* protos = ws;                       // 512000
    float* Xn     = protos + 512000;          // 256000
    float* W      = Xn + 256000;              // 1048576
    float* Ppart  = W + 1048576;              // 524288
    float* Qpart  = Ppart + 524288;           // 1048576
    float* enc    = Qpart + 1048576;          // 512000
    float* rsinv  = enc + 512000;             // 1024
    int*   cnt    = (int*)(rsinv + 1024);     // 1024
    int*   perm   = cnt + 1024;               // 512000

    hipMemsetAsync(cnt, 0, CP * sizeof(int), stream);
    fill_kernel<<<(N_IMG + 255) / 256, 256, 0, stream>>>(labels, cnt, perm, N_IMG);
    gather_kernel<<<C_CLS, 256, 0, stream>>>(image_feats, cnt, perm, protos);

    // stage 1: enc = softmax(maskexp(cos(p,p))) @ attributes, p = attributes@att_h
    proj_kernel<<<dim3(8, 32, 2), 256, 0, stream>>>(attributes, att_h, Ppart);
    norm_kernel<<<C_CLS, 256, 0, stream>>>(Ppart, Xn);
    score_kernel<<<dim3(32, 32), 256, 0, stream>>>(Xn, W);
    rowsum_kernel<<<C_CLS, 256, 0, stream>>>(W, rsinv);
    mm_kernel<<<dim3(8, 32, 2), 256, 0, stream>>>(W, attributes, nullptr, Qpart);
    combine_kernel<<<500, 256, 0, stream>>>(Qpart, rsinv, enc);

    // stage 2: out = softmax(maskexp(cos(q,q))) @ protos[tpl], q = enc@att_g
    proj_kernel<<<dim3(8, 32, 2), 256, 0, stream>>>(enc, att_g, Ppart);
    norm_kernel<<<C_CLS, 256, 0, stream>>>(Ppart, Xn);
    score_kernel<<<dim3(32, 32), 256, 0, stream>>>(Xn, W);
    rowsum_kernel<<<C_CLS, 256, 0, stream>>>(W, rsinv);
    mm_kernel<<<dim3(8, 32, 2), 256, 0, stream>>>(W, protos, tpl, Qpart);
    combine_kernel<<<500, 256, 0, stream>>>(Qpart, rsinv, out);
}

// Round 4
// 470.284 us; speedup vs baseline: 1.7343x; 1.0095x over previous
//
#include <hip/hip_runtime.h>

#define N_IMG 100000
#define C_CLS 1000
#define CP    1024    // padded class count
#define DIM   512     // att_dim == img_dim
#define HPROJ 256     // H
#define CAP   512     // per-class bucket capacity

// ---------------------------------------------------------------------------
// K0: one pass over labels -> per-class row lists. cnt[] must be zeroed.
// ---------------------------------------------------------------------------
__global__ __launch_bounds__(256) void fill_kernel(
    const int* __restrict__ labels, int* __restrict__ cnt,
    int* __restrict__ perm, int n)
{
    const int i = blockIdx.x * 256 + threadIdx.x;
    if (i < n) {
        const int c = labels[i];
        const int p = atomicAdd(&cnt[c], 1);
        if (p < CAP) perm[c * CAP + p] = i;
    }
}

// ---------------------------------------------------------------------------
// K1: per-class mean; float4 loads, 2 col-halves x 4 row streams.
// ---------------------------------------------------------------------------
__global__ __launch_bounds__(256) void gather_kernel(
    const float* __restrict__ image_feats,   // [N, 512]
    const int*   __restrict__ cnt,
    const int*   __restrict__ perm,
    float*       __restrict__ protos)        // [1000, 512]
{
    __shared__ int    s_list[CAP];
    __shared__ float4 s_acc[128];
    const int c = blockIdx.x;
    const int t = threadIdx.x;
    const int n = min(cnt[c], CAP);
    for (int m = t; m < n; m += 256) s_list[m] = perm[c * CAP + m];
    __syncthreads();
    const int half = t >> 7;          // which rows (even/odd list slots)
    const int tc   = t & 127;         // 4-float column group
    float4 a0 = {0,0,0,0}, a1 = {0,0,0,0}, a2 = {0,0,0,0}, a3 = {0,0,0,0};
    int m = half;
    for (; m + 6 < n; m += 8) {
        const float4 v0 = *(const float4*)(image_feats + (size_t)s_list[m]     * DIM + 4 * tc);
        const float4 v1 = *(const float4*)(image_feats + (size_t)s_list[m + 2] * DIM + 4 * tc);
        const float4 v2 = *(const float4*)(image_feats + (size_t)s_list[m + 4] * DIM + 4 * tc);
        const float4 v3 = *(const float4*)(image_feats + (size_t)s_list[m + 6] * DIM + 4 * tc);
        a0.x += v0.x; a0.y += v0.y; a0.z += v0.z; a0.w += v0.w;
        a1.x += v1.x; a1.y += v1.y; a1.z += v1.z; a1.w += v1.w;
        a2.x += v2.x; a2.y += v2.y; a2.z += v2.z; a2.w += v2.w;
        a3.x += v3.x; a3.y += v3.y; a3.z += v3.z; a3.w += v3.w;
    }
    for (; m < n; m += 2) {
        const float4 v0 = *(const float4*)(image_feats + (size_t)s_list[m] * DIM + 4 * tc);
        a0.x += v0.x; a0.y += v0.y; a0.z += v0.z; a0.w += v0.w;
    }
    a0.x += a1.x + a2.x + a3.x; a0.y += a1.y + a2.y + a3.y;
    a0.z += a1.z + a2.z + a3.z; a0.w += a1.w + a2.w + a3.w;
    if (half) s_acc[tc] = a0;
    __syncthreads();
    if (!half) {
        const float4 o = s_acc[tc];
        const float inv = 1.0f / (float)n;
        float4 r;
        r.x = (a0.x + o.x) * inv; r.y = (a0.y + o.y) * inv;
        r.z = (a0.z + o.z) * inv; r.w = (a0.w + o.w) * inv;
        *(float4*)(protos + (size_t)c * DIM + 4 * tc) = r;
    }
}

// ---------------------------------------------------------------------------
// K2: P[kz] = A_eff @ Wm partial GEMM. Tile 32x32, 2x2/thread, split-K x2.
// grid(8, 32, 2). A_eff[i] = A0[i]  or  (Q0[i]+Q1[i])/rsum[i]  (fused combine).
// ---------------------------------------------------------------------------
__global__ __launch_bounds__(256) void proj_kernel(
    const float* __restrict__ A0,    // [1000, 512] or nullptr
    const float* __restrict__ Qp,    // [2][1024][512] or nullptr
    const float* __restrict__ rsum,  // [1024] or nullptr
    const float* __restrict__ Wm,    // [512, 256]
    float*       __restrict__ P)     // [2][1024][256]
{
    __shared__ float At[64][34];    // k-major
    __shared__ float Wt[64][36];    // k-major
    const int t  = threadIdx.x;
    const int j0 = blockIdx.x * 32;
    const int i0 = blockIdx.y * 32;
    const int kz = blockIdx.z;
    const int tx = t & 15, ty = t >> 4;
    float a00 = 0.f, a01 = 0.f, a10 = 0.f, a11 = 0.f;
    for (int ch = 0; ch < 4; ++ch) {
        const int kb = kz * 256 + ch * 64;
        __syncthreads();
        for (int l = t; l < 512; l += 256) {
            const int r = l >> 4, f = l & 15;
            const int row = min(i0 + r, C_CLS - 1);
            float4 v;
            if (A0) {
                v = *(const float4*)(A0 + (size_t)row * DIM + kb + 4 * f);
            } else {
                const float4 q0 = *(const float4*)(Qp + (size_t)row * DIM + kb + 4 * f);
                const float4 q1 = *(const float4*)(Qp + (size_t)CP * DIM + (size_t)row * DIM + kb + 4 * f);
                const float rs = 1.0f / rsum[row];
                v.x = (q0.x + q1.x) * rs; v.y = (q0.y + q1.y) * rs;
                v.z = (q0.z + q1.z) * rs; v.w = (q0.w + q1.w) * rs;
            }
            At[4*f+0][r] = v.x; At[4*f+1][r] = v.y; At[4*f+2][r] = v.z; At[4*f+3][r] = v.w;
        }
        for (int l = t; l < 512; l += 256) {
            const int kk = l >> 3, f = l & 7;
            *(float4*)&Wt[kk][4*f] =
                *(const float4*)(Wm + (size_t)(kb + kk) * HPROJ + j0 + 4 * f);
        }
        __syncthreads();
#pragma unroll 8
        for (int kk = 0; kk < 64; ++kk) {
            const float2 a = *(const float2*)&At[kk][2 * ty];
            const float2 b = *(const float2*)&Wt[kk][2 * tx];
            a00 = fmaf(a.x, b.x, a00); a01 = fmaf(a.x, b.y, a01);
            a10 = fmaf(a.y, b.x, a10); a11 = fmaf(a.y, b.y, a11);
        }
    }
    float* dst = P + (size_t)kz * CP * HPROJ;
    const int i = i0 + 2 * ty;
    *(float2*)(dst + (size_t)i * HPROJ + j0 + 2 * tx) = make_float2(a00, a01);
    *(float2*)(dst + (size_t)(i + 1) * HPROJ + j0 + 2 * tx) = make_float2(a10, a11);
}

// ---------------------------------------------------------------------------
// K3: row-normalize (P0+P1), write TRANSPOSED XnT[256][1024]. 4 rows/block,
// grid(250). float4 store into XnT rows.
// ---------------------------------------------------------------------------
__global__ __launch_bounds__(256) void norm_kernel(
    const float* __restrict__ P, float* __restrict__ XnT)
{
    __shared__ float red[4][4];
    __shared__ float srn[4];
    const int i0 = blockIdx.x * 4;
    const int t  = threadIdx.x;
    float x[4], ss[4];
#pragma unroll
    for (int u = 0; u < 4; ++u) {
        x[u] = P[(size_t)(i0 + u) * HPROJ + t]
             + P[(size_t)CP * HPROJ + (size_t)(i0 + u) * HPROJ + t];
        ss[u] = x[u] * x[u];
    }
#pragma unroll
    for (int off = 32; off > 0; off >>= 1)
#pragma unroll
        for (int u = 0; u < 4; ++u) ss[u] += __shfl_down(ss[u], off);
    if ((t & 63) == 0) {
        const int wv = t >> 6;
#pragma unroll
        for (int u = 0; u < 4; ++u) red[u][wv] = ss[u];
    }
    __syncthreads();
    if (t < 4) srn[t] = rsqrtf(red[t][0] + red[t][1] + red[t][2] + red[t][3]);
    __syncthreads();
    float4 tv;
    tv.x = x[0] * srn[0]; tv.y = x[1] * srn[1];
    tv.z = x[2] * srn[2]; tv.w = x[3] * srn[3];
    *(float4*)(XnT + (size_t)t * CP + i0) = tv;
}

// ---------------------------------------------------------------------------
// K4: WT[j][i] = maskexp(cos_ij); fused row-sum (atomicAdd into rsum, must be
// pre-zeroed). Tile 64x64, 4x4/thread, K=256. grid(16, 16).
// Writes ALL j rows 0..1023 (j>=1000 -> 0) so mm's K-pad contributes zero.
// ---------------------------------------------------------------------------
__global__ __launch_bounds__(256) void score_kernel(
    const float* __restrict__ XnT,   // [256][1024]
    float*       __restrict__ WT,    // [1024][1024]
    float*       __restrict__ rsum)  // [1024], zeroed
{
    __shared__ float Xi[64][68];
    __shared__ float Xj[64][68];
    __shared__ float s_rp[64][17];
    const int t  = threadIdx.x;
    const int j0 = blockIdx.x * 64;
    const int i0 = blockIdx.y * 64;
    const int tx = t & 15, ty = t >> 4;
    float acc[4][4] = {};
    for (int ch = 0; ch < 4; ++ch) {
        const int kb = ch * 64;
        __syncthreads();
        for (int l = t; l < 1024; l += 256) {
            const int kk = l >> 4, f = l & 15;
            const float* src = XnT + (size_t)(kb + kk) * CP;
            *(float4*)&Xi[kk][4 * f] = *(const float4*)(src + i0 + 4 * f);
            *(float4*)&Xj[kk][4 * f] = *(const float4*)(src + j0 + 4 * f);
        }
        __syncthreads();
#pragma unroll 8
        for (int kk = 0; kk < 64; ++kk) {
            const float4 a = *(const float4*)&Xi[kk][4 * ty];
            const float4 b = *(const float4*)&Xj[kk][4 * tx];
            const float av[4] = {a.x, a.y, a.z, a.w};
            const float bv[4] = {b.x, b.y, b.z, b.w};
#pragma unroll
            for (int u = 0; u < 4; ++u)
#pragma unroll
                for (int v = 0; v < 4; ++v)
                    acc[u][v] = fmaf(av[u], bv[v], acc[u][v]);
        }
    }
    float rp[4] = {0.f, 0.f, 0.f, 0.f};
#pragma unroll
    for (int v = 0; v < 4; ++v) {
        const int j = j0 + 4 * tx + v;
        const bool jv = (j < C_CLS);
        float4 o;
#pragma unroll
        for (int u = 0; u < 4; ++u) {
            const float d = acc[u][v];
            const float w = (jv && d > 0.5f) ? __expf(10.f * d) : 0.f;
            ((float*)&o)[u] = w;
            rp[u] += w;
        }
        *(float4*)(WT + (size_t)j * CP + i0 + 4 * ty) = o;
    }
#pragma unroll
    for (int u = 0; u < 4; ++u) s_rp[4 * ty + u][tx] = rp[u];
    __syncthreads();
    if (t < 64) {
        float s = 0.f;
#pragma unroll 16
        for (int k = 0; k < 16; ++k) s += s_rp[t][k];
        const int i = i0 + t;
        if (i < C_CLS) atomicAdd(&rsum[i], s);
    }
}

// ---------------------------------------------------------------------------
// K5: Q[kz] = W @ Vg partial GEMM from WT. Tile 64x64, 4x4/thread, split-K x2
// over K=1024 (WT rows >=1000 are zeros). grid(8, 16, 2).
// ---------------------------------------------------------------------------
__global__ __launch_bounds__(256) void mm_kernel(
    const float* __restrict__ WT,   // [1024][1024]
    const float* __restrict__ V,    // [1000, 512]
    const int*   __restrict__ vidx, // nullptr or [1000]
    float*       __restrict__ Q)    // [2][1024][512]
{
    __shared__ float Wt[64][68];    // [k][i]
    __shared__ float Vt[64][68];    // [k][c]
    const int t  = threadIdx.x;
    const int c0 = blockIdx.x * 64;
    const int i0 = blockIdx.y * 64;
    const int kz = blockIdx.z;
    const int tx = t & 15, ty = t >> 4;
    float acc[4][4] = {};
    for (int ch = 0; ch < 8; ++ch) {
        const int kb = kz * 512 + ch * 64;
        __syncthreads();
        for (int l = t; l < 1024; l += 256) {
            const int kk = l >> 4, f = l & 15;
            *(float4*)&Wt[kk][4 * f] =
                *(const float4*)(WT + (size_t)(kb + kk) * CP + i0 + 4 * f);
            const int jc = min(kb + kk, C_CLS - 1);
            const int vr = vidx ? vidx[jc] : jc;
            *(float4*)&Vt[kk][4 * f] =
                *(const float4*)(V + (size_t)vr * DIM + c0 + 4 * f);
        }
        __syncthreads();
#pragma unroll 8
        for (int kk = 0; kk < 64; ++kk) {
            const float4 w = *(const float4*)&Wt[kk][4 * ty];
            const float4 v = *(const float4*)&Vt[kk][4 * tx];
            const float wv[4] = {w.x, w.y, w.z, w.w};
            const float vv[4] = {v.x, v.y, v.z, v.w};
#pragma unroll
            for (int u = 0; u < 4; ++u)
#pragma unroll
                for (int cv = 0; cv < 4; ++cv)
                    acc[u][cv] = fmaf(wv[u], vv[cv], acc[u][cv]);
        }
    }
    float* dst = Q + (size_t)kz * CP * DIM;
#pragma unroll
    for (int u = 0; u < 4; ++u) {
        const int i = i0 + 4 * ty + u;
        float4 o = {acc[u][0], acc[u][1], acc[u][2], acc[u][3]};
        *(float4*)(dst + (size_t)i * DIM + c0 + 4 * tx) = o;
    }
}

// ---------------------------------------------------------------------------
// K6: Out[i,c] = (Q0[i,c]+Q1[i,c]) / rsum[i], i < 1000. grid(500).
// ---------------------------------------------------------------------------
__global__ __launch_bounds__(256) void combine_kernel(
    const float* __restrict__ Q, const float* __restrict__ rsum,
    float* __restrict__ Out)    // [1000, 512]
{
    const int idx = blockIdx.x * 256 + threadIdx.x;   // f4 index
    if (idx < C_CLS * DIM / 4) {
        const int i = idx >> 7;
        const float4 a = *(const float4*)(Q + (size_t)4 * idx);
        const float4 b = *(const float4*)(Q + (size_t)CP * DIM + (size_t)4 * idx);
        const float s = 1.0f / rsum[i];
        float4 o;
        o.x = s * (a.x + b.x); o.y = s * (a.y + b.y);
        o.z = s * (a.z + b.z); o.w = s * (a.w + b.w);
        *(float4*)(Out + (size_t)4 * idx) = o;
    }
}

// ---------------------------------------------------------------------------
extern "C" void kernel_launch(void* const* d_in, const int* in_sizes, int n_in,
                              void* d_out, int out_size, void* d_ws, size_t ws_size,
                              hipStream_t stream) {
    const float* image_feats = (const float*)d_in[0];  // [100000, 512]
    const float* attributes  = (const float*)d_in[1];  // [1000, 512]
    const float* att_g       = (const float*)d_in[2];  // [512, 256]
    const float* att_h       = (const float*)d_in[3];  // [512, 256]
    const int*   labels      = (const int*)d_in[4];    // [100000]
    const int*   tpl         = (const int*)d_in[5];    // [1000]
    float* out = (float*)d_out;                        // [1000, 512]

    float* ws     = (float*)d_ws;
    float* protos = ws;                       // 512000
    float* XnT    = protos + 512000;          // 262144
    float* WT     = XnT + 262144;             // 1048576
    float* Ppart  = WT + 1048576;             // 524288
    float* Qpart  = Ppart + 524288;           // 1048576
    // zero-block: cnt | rsum1 | rsum2 (one memset)
    int*   cnt    = (int*)(Qpart + 1048576);  // 1024
    float* rsum1  = (float*)(cnt + 1024);     // 1024
    float* rsum2  = rsum1 + 1024;             // 1024
    int*   perm   = (int*)(rsum2 + 1024);     // 512000

    hipMemsetAsync(cnt, 0, 3 * 1024 * sizeof(int), stream);
    fill_kernel<<<(N_IMG + 255) / 256, 256, 0, stream>>>(labels, cnt, perm, N_IMG);
    gather_kernel<<<C_CLS, 256, 0, stream>>>(image_feats, cnt, perm, protos);

    // stage 1: enc-related (kept in Qpart+rsum1, combined inside stage-2 proj)
    proj_kernel<<<dim3(8, 32, 2), 256, 0, stream>>>(attributes, nullptr, nullptr, att_h, Ppart);
    norm_kernel<<<250, 256, 0, stream>>>(Ppart, XnT);
    score_kernel<<<dim3(16, 16), 256, 0, stream>>>(XnT, WT, rsum1);
    mm_kernel<<<dim3(8, 16, 2), 256, 0, stream>>>(WT, attributes, nullptr, Qpart);

    // stage 2
    proj_kernel<<<dim3(8, 32, 2), 256, 0, stream>>>(nullptr, Qpart, rsum1, att_g, Ppart);
    norm_kernel<<<250, 256, 0, stream>>>(Ppart, XnT);
    score_kernel<<<dim3(16, 16), 256, 0, stream>>>(XnT, WT, rsum2);
    mm_kernel<<<dim3(8, 16, 2), 256, 0, stream>>>(WT, protos, tpl, Qpart);
    combine_kernel<<<500, 256, 0, stream>>>(Qpart, rsum2, out);
}